// Round 2
// baseline (453.224 us; speedup 1.0000x reference)
//
#include <hip/hip_runtime.h>

// CapsuleNet forward, fused, fp32 — LDS-traffic-optimized round.
// Key changes vs prev: priors written to LDS ONCE per group (readers apply
// coupling p from a small table), all LDS traffic vectorized to float4 with
// conflict-free strides (SROW=20, CROW=12, PROW=37), M_INNER=4 halves barriers.
constexpr int OC = 10, NI = 36, OD = 16, IL = 8;
constexpr int M_BLK   = 16;            // batches per block
constexpr int M_INNER = 4;             // batches per routing pass
constexpr int NGROUPS = M_BLK / M_INNER;
constexpr int NT      = 768;
constexpr int SROW = 20;   // spl row stride (16 data + 4 pad); b128 writes hit 8 uniform bank-groups
constexpr int CROW = 12;   // caps row stride; 12i mod 32 has 8 distinct b128 start banks
constexpr int PROW = 37;   // ptab row stride; 37k mod 32 spreads starts (odd, coprime-ish)

__global__ __launch_bounds__(NT, 1)
void capsnet_kernel(const float* __restrict__ xg,
                    const float* __restrict__ cwg,
                    const float* __restrict__ lwg,
                    float* __restrict__ outg) {
    __shared__ float xs[M_BLK * 9];                    //  576 B
    __shared__ float cw[288];                          // 1152 B
    __shared__ float caps_s[M_BLK * NI * CROW];        // 27648 B
    __shared__ float spl[M_INNER * OC * NI * SROW];    // 115200 B  raw priors [m][o][i][20]
    __shared__ float el[M_INNER * NI * OC];            // 5760 B   exp(logits) [m][i][o]
    __shared__ float ptab[M_INNER * OC * PROW];        // 5920 B   coupling p [m][o][i]
    __shared__ float outl[M_INNER * OC * OD];          // 2560 B   out vectors
    // total ~158.8 KB < 160 KiB

    const int t  = threadIdx.x;
    const int b0 = blockIdx.x * M_BLK;

    if (t < M_BLK * 9) xs[t] = xg[b0 * 9 + t];
    if (t < 288)       cw[t] = cwg[t];

    const bool act = t < 2 * OC * NI;   // 720
    const int o  = t / 72;
    const int r  = t % 72;
    const int i  = r >> 1;
    const int dh = r & 1;

    float4 w4[16];   // 64 lin_w floats, register/AGPR-resident, reused for all 16 batches
    if (act) {
        const float4* wp = reinterpret_cast<const float4*>(
            lwg + ((o * NI + i) * OD + dh * 8) * IL);
        #pragma unroll
        for (int j = 0; j < 16; ++j) w4[j] = wp[j];
    }
    __syncthreads();

    // ---- conv (1->32ch, 3x3, pad 1) + squash -> caps_s[(m*36+i)*12 + l] ----
    if (t < M_BLK * NI) {   // 576
        const int m  = t / NI;
        const int ci = t % NI;
        const int cg = ci & 3;
        const int wx = (ci >> 2) % 3;
        const int hx = ci / 12;
        float acc[IL] = {0.f,0.f,0.f,0.f,0.f,0.f,0.f,0.f};
        #pragma unroll
        for (int kh = 0; kh < 3; ++kh) {
            const int xh = hx + kh - 1;
            if (xh < 0 || xh > 2) continue;
            #pragma unroll
            for (int kw = 0; kw < 3; ++kw) {
                const int xw = wx + kw - 1;
                if (xw < 0 || xw > 2) continue;
                const float xv = xs[m * 9 + xh * 3 + xw];
                #pragma unroll
                for (int l = 0; l < IL; ++l)
                    acc[l] += xv * cw[(cg * 8 + l) * 9 + kh * 3 + kw];
            }
        }
        float n2 = 0.f;
        #pragma unroll
        for (int l = 0; l < IL; ++l) n2 += acc[l] * acc[l];
        const float sc = n2 / (1.f + n2) * rsqrtf(n2 + 1e-8f);
        float4* cp = reinterpret_cast<float4*>(caps_s + (m * NI + ci) * CROW);
        cp[0] = make_float4(acc[0]*sc, acc[1]*sc, acc[2]*sc, acc[3]*sc);
        cp[1] = make_float4(acc[4]*sc, acc[5]*sc, acc[6]*sc, acc[7]*sc);
    }
    __syncthreads();

    for (int grp = 0; grp < NGROUPS; ++grp) {
        float P[M_INNER][8];
        float lg[M_INNER];
        // ---- einsum into regs + single raw-P write to spl ----
        if (act) {
            #pragma unroll
            for (int m = 0; m < M_INNER; ++m) {
                const float4* cp = reinterpret_cast<const float4*>(
                    caps_s + ((grp * M_INNER + m) * NI + i) * CROW);
                const float4 c0 = cp[0], c1 = cp[1];
                #pragma unroll
                for (int d = 0; d < 8; ++d) {
                    const float4 a  = w4[2*d], b4 = w4[2*d + 1];
                    P[m][d] = a.x*c0.x + a.y*c0.y + a.z*c0.z + a.w*c0.w
                            + b4.x*c1.x + b4.y*c1.y + b4.z*c1.z + b4.w*c1.w;
                }
                float4* sp = reinterpret_cast<float4*>(
                    spl + ((m * OC + o) * NI + i) * SROW + dh * 8);
                sp[0] = make_float4(P[m][0], P[m][1], P[m][2], P[m][3]);
                sp[1] = make_float4(P[m][4], P[m][5], P[m][6], P[m][7]);
                lg[m] = 0.f;
            }
        }
        __syncthreads();   // B1: spl ready

        for (int it = 0; it < 3; ++it) {
            // ---- reduce over i + squash: 160 threads, all-b128 reads ----
            if (t < M_INNER * OC * 4) {   // 160: (rm, ro, dq)
                const int rm = t / 40;
                const int rr = t % 40;
                const int ro = rr >> 2;
                const int dq = rr & 3;
                const float4* base = reinterpret_cast<const float4*>(
                    spl + (rm * OC + ro) * NI * SROW) + dq;   // row stride = 5 float4
                float4 s4 = make_float4(0.f, 0.f, 0.f, 0.f);
                if (it == 0) {
                    #pragma unroll
                    for (int ii = 0; ii < NI; ++ii) {
                        const float4 v = base[ii * 5];
                        s4.x += v.x; s4.y += v.y; s4.z += v.z; s4.w += v.w;
                    }
                    s4.x *= 0.1f; s4.y *= 0.1f; s4.z *= 0.1f; s4.w *= 0.1f;
                } else {
                    const float* pr = ptab + (rm * OC + ro) * PROW;
                    #pragma unroll
                    for (int ii = 0; ii < NI; ++ii) {
                        const float pv = pr[ii];
                        const float4 v = base[ii * 5];
                        s4.x += pv * v.x; s4.y += pv * v.y;
                        s4.z += pv * v.z; s4.w += pv * v.w;
                    }
                }
                float n2 = s4.x*s4.x + s4.y*s4.y + s4.z*s4.z + s4.w*s4.w;
                n2 += __shfl_xor(n2, 1);
                n2 += __shfl_xor(n2, 2);
                const float sc = n2 / (1.f + n2) * rsqrtf(n2 + 1e-8f);
                const float4 ov = make_float4(s4.x*sc, s4.y*sc, s4.z*sc, s4.w*sc);
                if (it == 2)
                    *reinterpret_cast<float4*>(
                        outg + (b0 + grp * M_INNER + rm) * (OC * OD) + ro * OD + dq * 4) = ov;
                else
                    *reinterpret_cast<float4*>(
                        outl + rm * (OC * OD) + ro * OD + dq * 4) = ov;
            }
            __syncthreads();   // B2: out ready (and spl reads done before next grp write)
            if (it == 2) break;

            // ---- agreement: logits += P . out ; write exp(logits) ----
            if (act) {
                #pragma unroll
                for (int m = 0; m < M_INNER; ++m) {
                    const float4* omp = reinterpret_cast<const float4*>(
                        outl + m * (OC * OD) + o * OD + dh * 8);
                    const float4 oa = omp[0], ob = omp[1];
                    float dp = P[m][0]*oa.x + P[m][1]*oa.y + P[m][2]*oa.z + P[m][3]*oa.w
                             + P[m][4]*ob.x + P[m][5]*ob.y + P[m][6]*ob.z + P[m][7]*ob.w;
                    dp += __shfl_xor(dp, 1);
                    lg[m] += dp;
                    if (dh == 0) el[(m * NI + i) * OC + o] = __expf(lg[m]);
                }
            }
            __syncthreads();   // B3: el ready

            // ---- softmax over o -> coupling table p[m][o][i] ----
            if (t < M_INNER * NI) {   // 144
                const int em = t / NI;
                const int ei = t % NI;
                const float* er = el + (em * NI + ei) * OC;
                float ss = 0.f;
                #pragma unroll
                for (int o2 = 0; o2 < OC; ++o2) ss += er[o2];
                const float inv = 1.f / ss;
                #pragma unroll
                for (int o2 = 0; o2 < OC; ++o2)
                    ptab[(em * OC + o2) * PROW + ei] = er[o2] * inv;
            }
            __syncthreads();   // B4: ptab ready for next iteration
        }
    }
}

extern "C" void kernel_launch(void* const* d_in, const int* in_sizes, int n_in,
                              void* d_out, int out_size, void* d_ws, size_t ws_size,
                              hipStream_t stream) {
    const float* x  = (const float*)d_in[0];   // [B,1,3,3]
    const float* cwp = (const float*)d_in[1];  // [32,1,3,3]
    const float* lw = (const float*)d_in[2];   // [10,36,16,8]
    float* out = (float*)d_out;                // [B,10,16]
    const int B = in_sizes[0] / 9;             // 16384
    dim3 grid(B / M_BLK), block(NT);
    capsnet_kernel<<<grid, block, 0, stream>>>(x, cwp, lw, out);
}

// Round 3
// 337.683 us; speedup vs baseline: 1.3422x; 1.3422x over previous
//
#include <hip/hip_runtime.h>

// CapsuleNet forward, fused, fp32 — R3: spill-free + 2 blocks/CU.
// vs R2: M_INNER=2 (P regs = 16 floats, no scratch spill), weights streamed
// from L2 per group (vmem pipe is idle), LDS shrunk to 79.9 KB so two blocks
// co-reside per CU and overlap VALU/LDS/barrier phases.
constexpr int OC = 10, NI = 36, OD = 16, IL = 8;
constexpr int M_BLK   = 8;             // batches per block
constexpr int M_INNER = 2;             // batches per routing pass
constexpr int NGROUPS = M_BLK / M_INNER;   // 4
constexpr int NT      = 768;
constexpr int SROW = 20;   // spl row stride: 8 uniform b128 start banks
constexpr int CROW = 12;   // caps row stride: 16B-aligned, 8 start banks
constexpr int PROW = 36;   // ptab row stride: conflict-free for reduce pattern

__global__ __launch_bounds__(NT, 6)
void capsnet_kernel(const float* __restrict__ xg,
                    const float* __restrict__ cwg,
                    const float* __restrict__ lwg,
                    float* __restrict__ outg) {
    __shared__ float xs[M_BLK * 9];                    //   288 B
    __shared__ float cw[288];                          //  1152 B
    __shared__ float caps_s[M_BLK * NI * CROW];        // 13824 B
    __shared__ float spl[M_INNER * OC * NI * SROW];    // 57600 B raw priors
    __shared__ float el[M_INNER * NI * OC];            //  2880 B exp(logits)
    __shared__ float ptab[M_INNER * OC * PROW];        //  2880 B coupling p
    __shared__ float outl[M_INNER * OC * OD];          //  1280 B
    // total 79,904 B -> 2 blocks/CU

    const int t  = threadIdx.x;
    const int b0 = blockIdx.x * M_BLK;

    if (t < M_BLK * 9) xs[t] = xg[b0 * 9 + t];
    if (t < 288)       cw[t] = cwg[t];

    const bool act = t < 2 * OC * NI;   // 720
    const int o  = t / 72;
    const int r  = t % 72;
    const int i  = r >> 1;
    const int dh = r & 1;
    __syncthreads();

    // ---- conv (1->32ch, 3x3, pad 1) + squash -> caps_s ----
    if (t < M_BLK * NI) {   // 288
        const int m  = t / NI;
        const int ci = t % NI;
        const int cg = ci & 3;
        const int wx = (ci >> 2) % 3;
        const int hx = ci / 12;
        float acc[IL] = {0.f,0.f,0.f,0.f,0.f,0.f,0.f,0.f};
        #pragma unroll
        for (int kh = 0; kh < 3; ++kh) {
            const int xh = hx + kh - 1;
            if (xh < 0 || xh > 2) continue;
            #pragma unroll
            for (int kw = 0; kw < 3; ++kw) {
                const int xw = wx + kw - 1;
                if (xw < 0 || xw > 2) continue;
                const float xv = xs[m * 9 + xh * 3 + xw];
                #pragma unroll
                for (int l = 0; l < IL; ++l)
                    acc[l] += xv * cw[(cg * 8 + l) * 9 + kh * 3 + kw];
            }
        }
        float n2 = 0.f;
        #pragma unroll
        for (int l = 0; l < IL; ++l) n2 += acc[l] * acc[l];
        const float sc = n2 / (1.f + n2) * rsqrtf(n2 + 1e-8f);
        float4* cp = reinterpret_cast<float4*>(caps_s + (m * NI + ci) * CROW);
        cp[0] = make_float4(acc[0]*sc, acc[1]*sc, acc[2]*sc, acc[3]*sc);
        cp[1] = make_float4(acc[4]*sc, acc[5]*sc, acc[6]*sc, acc[7]*sc);
    }
    __syncthreads();

    for (int grp = 0; grp < NGROUPS; ++grp) {
        float P0[8], P1[8];
        float lg0 = 0.f, lg1 = 0.f;
        // ---- einsum (weights streamed from L2) + raw-P write to spl ----
        if (act) {
            const float4* cpa = reinterpret_cast<const float4*>(
                caps_s + ((grp * 2 + 0) * NI + i) * CROW);
            const float4* cpb = reinterpret_cast<const float4*>(
                caps_s + ((grp * 2 + 1) * NI + i) * CROW);
            const float4 c00 = cpa[0], c01 = cpa[1];
            const float4 c10 = cpb[0], c11 = cpb[1];
            const float4* wp = reinterpret_cast<const float4*>(
                lwg + ((o * NI + i) * OD + dh * 8) * IL);
            #pragma unroll
            for (int d = 0; d < 8; ++d) {
                const float4 a = wp[2*d], b = wp[2*d + 1];
                P0[d] = a.x*c00.x + a.y*c00.y + a.z*c00.z + a.w*c00.w
                      + b.x*c01.x + b.y*c01.y + b.z*c01.z + b.w*c01.w;
                P1[d] = a.x*c10.x + a.y*c10.y + a.z*c10.z + a.w*c10.w
                      + b.x*c11.x + b.y*c11.y + b.z*c11.z + b.w*c11.w;
            }
            float4* sp0 = reinterpret_cast<float4*>(
                spl + ((0 * OC + o) * NI + i) * SROW + dh * 8);
            float4* sp1 = reinterpret_cast<float4*>(
                spl + ((1 * OC + o) * NI + i) * SROW + dh * 8);
            sp0[0] = make_float4(P0[0], P0[1], P0[2], P0[3]);
            sp0[1] = make_float4(P0[4], P0[5], P0[6], P0[7]);
            sp1[0] = make_float4(P1[0], P1[1], P1[2], P1[3]);
            sp1[1] = make_float4(P1[4], P1[5], P1[6], P1[7]);
        }
        __syncthreads();   // B1: spl ready

        for (int it = 0; it < 3; ++it) {
            // ---- reduce over i + squash: 160 threads (mo, dq, ih) ----
            if (t < M_INNER * OC * 8) {   // 160
                const int mo = t >> 3;          // m*10+o
                const int dq = (t >> 1) & 3;
                const int ih = t & 1;
                const float* base = spl + mo * NI * SROW + dq * 4;
                float4 s4 = make_float4(0.f, 0.f, 0.f, 0.f);
                if (it == 0) {
                    #pragma unroll
                    for (int ii = 0; ii < 18; ++ii) {
                        const float4 v = *reinterpret_cast<const float4*>(
                            base + (ih * 18 + ii) * SROW);
                        s4.x += v.x; s4.y += v.y; s4.z += v.z; s4.w += v.w;
                    }
                    s4.x *= 0.1f; s4.y *= 0.1f; s4.z *= 0.1f; s4.w *= 0.1f;
                } else {
                    const float* pr = ptab + mo * PROW;
                    #pragma unroll
                    for (int ii = 0; ii < 18; ++ii) {
                        const float pv = pr[ih * 18 + ii];
                        const float4 v = *reinterpret_cast<const float4*>(
                            base + (ih * 18 + ii) * SROW);
                        s4.x += pv * v.x; s4.y += pv * v.y;
                        s4.z += pv * v.z; s4.w += pv * v.w;
                    }
                }
                // reduce over ih (lane bit 0)
                s4.x += __shfl_xor(s4.x, 1);
                s4.y += __shfl_xor(s4.y, 1);
                s4.z += __shfl_xor(s4.z, 1);
                s4.w += __shfl_xor(s4.w, 1);
                float n2 = s4.x*s4.x + s4.y*s4.y + s4.z*s4.z + s4.w*s4.w;
                n2 += __shfl_xor(n2, 2);   // dq bits are lane bits 1-2
                n2 += __shfl_xor(n2, 4);
                const float sc = n2 / (1.f + n2) * rsqrtf(n2 + 1e-8f);
                const float4 ov = make_float4(s4.x*sc, s4.y*sc, s4.z*sc, s4.w*sc);
                if (ih == 0) {
                    const int rm = mo / 10, ro = mo % 10;
                    if (it == 2)
                        *reinterpret_cast<float4*>(
                            outg + (b0 + grp * 2 + rm) * (OC*OD) + ro * OD + dq * 4) = ov;
                    else
                        *reinterpret_cast<float4*>(
                            outl + rm * (OC*OD) + ro * OD + dq * 4) = ov;
                }
            }
            __syncthreads();   // B2: out ready / spl reads done
            if (it == 2) break;

            // ---- agreement: logits += P . out ; write exp(logits) ----
            if (act) {
                const float4* om0 = reinterpret_cast<const float4*>(
                    outl + 0 * (OC*OD) + o * OD + dh * 8);
                const float4* om1 = reinterpret_cast<const float4*>(
                    outl + 1 * (OC*OD) + o * OD + dh * 8);
                const float4 oa = om0[0], ob = om0[1];
                const float4 oc = om1[0], od4 = om1[1];
                float dp0 = P0[0]*oa.x + P0[1]*oa.y + P0[2]*oa.z + P0[3]*oa.w
                          + P0[4]*ob.x + P0[5]*ob.y + P0[6]*ob.z + P0[7]*ob.w;
                float dp1 = P1[0]*oc.x + P1[1]*oc.y + P1[2]*oc.z + P1[3]*oc.w
                          + P1[4]*od4.x + P1[5]*od4.y + P1[6]*od4.z + P1[7]*od4.w;
                dp0 += __shfl_xor(dp0, 1);   // dh is lane bit 0
                dp1 += __shfl_xor(dp1, 1);
                lg0 += dp0;
                lg1 += dp1;
                if (dh == 0) {
                    el[(0 * NI + i) * OC + o] = __expf(lg0);
                    el[(1 * NI + i) * OC + o] = __expf(lg1);
                }
            }
            __syncthreads();   // B3: el ready

            // ---- softmax over o -> coupling table ptab[m][o][i] ----
            if (t < M_INNER * NI) {   // 72
                const int em = t / NI, ei = t % NI;
                const float* er = el + (em * NI + ei) * OC;
                float ss = 0.f;
                #pragma unroll
                for (int o2 = 0; o2 < OC; ++o2) ss += er[o2];
                const float inv = 1.f / ss;
                #pragma unroll
                for (int o2 = 0; o2 < OC; ++o2)
                    ptab[(em * OC + o2) * PROW + ei] = er[o2] * inv;
            }
            __syncthreads();   // B4: ptab ready
        }
    }
}

extern "C" void kernel_launch(void* const* d_in, const int* in_sizes, int n_in,
                              void* d_out, int out_size, void* d_ws, size_t ws_size,
                              hipStream_t stream) {
    const float* x   = (const float*)d_in[0];   // [B,1,3,3]
    const float* cwp = (const float*)d_in[1];   // [32,1,3,3]
    const float* lw  = (const float*)d_in[2];   // [10,36,16,8]
    float* out = (float*)d_out;                 // [B,10,16]
    const int B = in_sizes[0] / 9;              // 16384
    dim3 grid(B / M_BLK), block(NT);
    capsnet_kernel<<<grid, block, 0, stream>>>(x, cwp, lw, out);
}